// Round 1
// baseline (205.270 us; speedup 1.0000x reference)
//
#include <hip/hip_runtime.h>
#include <hip/hip_bf16.h>

// Problem constants
#define NB    32          // batch
#define NC    256         // channels
#define NPOS  1024        // H*W
#define NG    32          // groups
#define EPSV  1e-5f
#define QSC   0.0625f     // C^-0.5

typedef __attribute__((ext_vector_type(8))) __bf16 bfrag;   // MFMA A/B operand (4 VGPRs)
typedef __attribute__((ext_vector_type(4))) float  f32x4;   // MFMA C/D operand
typedef __attribute__((ext_vector_type(8))) short  s16x8;   // 16B bf16 payload
typedef __attribute__((ext_vector_type(4))) short  s16x4;

static __device__ __forceinline__ short f2b(float f) {
    __hip_bfloat16 h = __float2bfloat16(f);
    return __builtin_bit_cast(short, h);
}

// ---------------------------------------------------------------------------
// K0: weights fp32 [k][n] -> bf16 transposed [n][k]  (4 matrices: q,k,v,o)
// ---------------------------------------------------------------------------
__global__ __launch_bounds__(256) void prep_w(const float* __restrict__ wq,
                                              const float* __restrict__ wk,
                                              const float* __restrict__ wv,
                                              const float* __restrict__ wo,
                                              short* __restrict__ wt) {
    const int z = blockIdx.x >> 8;
    const int n = blockIdx.x & 255;
    const int k = threadIdx.x;
    const float* w = (z == 0) ? wq : (z == 1) ? wk : (z == 2) ? wv : wo;
    wt[(z * 256 + n) * 256 + k] = f2b(w[k * 256 + n]);
}

// ---------------------------------------------------------------------------
// K1a: GroupNorm partial sums.  grid = 32 b * 8 chunks, 256 thr.
// part[b][ch][g][2] = {sum, sumsq} over 128 positions x 8 channels
// ---------------------------------------------------------------------------
__global__ __launch_bounds__(256) void gn_part(const float* __restrict__ x,
                                               float* __restrict__ part) {
    const int b = blockIdx.x >> 3, ch = blockIdx.x & 7;
    const int t = threadIdx.x;
    const int c4 = t & 63;       // float4 index within a row (channel group = c4>>1)
    const int rr = t >> 6;       // 0..3
    float s1 = 0.f, s2 = 0.f;
    for (int i = 0; i < 32; ++i) {
        const int pos = ch * 128 + rr + (i << 2);
        const f32x4 v = *reinterpret_cast<const f32x4*>(x + (((b << 10) + pos) << 8) + (c4 << 2));
        s1 += v[0] + v[1] + v[2] + v[3];
        s2 += v[0]*v[0] + v[1]*v[1] + v[2]*v[2] + v[3]*v[3];
    }
    __shared__ float ls1[256], ls2[256];
    ls1[t] = s1; ls2[t] = s2;
    __syncthreads();
    if (t < 32) {
        float a1 = 0.f, a2 = 0.f;
        for (int r2 = 0; r2 < 4; ++r2)
            for (int e = 0; e < 2; ++e) {
                const int idx = r2 * 64 + t * 2 + e;
                a1 += ls1[idx]; a2 += ls2[idx];
            }
        part[((b * 8 + ch) * 32 + t) * 2 + 0] = a1;
        part[((b * 8 + ch) * 32 + t) * 2 + 1] = a2;
    }
}

// ---------------------------------------------------------------------------
// K1b: finalize stats -> per-(b,c) affine:  ft = x*cA + cB
// ---------------------------------------------------------------------------
__global__ __launch_bounds__(256) void gn_final(const float* __restrict__ part,
                                                const float* __restrict__ gns,
                                                const float* __restrict__ gnb,
                                                float* __restrict__ cA,
                                                float* __restrict__ cB) {
    const int b = blockIdx.x, c = threadIdx.x, g = c >> 3;
    float s1 = 0.f, s2 = 0.f;
    for (int ch = 0; ch < 8; ++ch) {
        s1 += part[((b * 8 + ch) * 32 + g) * 2 + 0];
        s2 += part[((b * 8 + ch) * 32 + g) * 2 + 1];
    }
    const float mean = s1 * (1.f / 8192.f);
    const float var  = s2 * (1.f / 8192.f) - mean * mean;
    const float rstd = rsqrtf(var + EPSV);
    const float a = rstd * gns[c];
    cA[(b << 8) + c] = a;
    cB[(b << 8) + c] = gnb[c] - mean * a;
}

// ---------------------------------------------------------------------------
// K2: fused GN-normalize + QKV projection.
// grid = 512 (64-row tiles), 256 thr = 4 waves, each wave a 64x64 n-slice.
// q is pre-scaled by C^-0.5.
// ---------------------------------------------------------------------------
__global__ __launch_bounds__(256) void qkv_gemm(const float* __restrict__ x,
                                                const float* __restrict__ cA,
                                                const float* __restrict__ cB,
                                                const short* __restrict__ wt,   // [3][256][256]
                                                const float* __restrict__ bq,
                                                const float* __restrict__ bk,
                                                const float* __restrict__ bv,
                                                short* __restrict__ qo,
                                                short* __restrict__ ko,
                                                short* __restrict__ vo) {
    __shared__ short At[64][264];   // 64 rows x 256 k  (stride 528B, 16B aligned)
    __shared__ short Bt[256][40];   // 256 n x 32 k

    const int t  = threadIdx.x;
    const int m0 = blockIdx.x * 64;
    const int b  = m0 >> 10;
    const int lane = t & 63, w = t >> 6;
    const int lr = lane & 15, lh = lane >> 4;

    // ---- A tile: load x, apply GN affine, convert to bf16 (once per block)
    {
        const int r = t >> 2, q4 = t & 3;
        const float* xrow = x + (m0 + r) * 256;
        const float* ca = cA + (b << 8);
        const float* cb = cB + (b << 8);
        for (int i = 0; i < 16; ++i) {
            const int c0 = (q4 + 4 * i) * 4;
            const f32x4 v  = *reinterpret_cast<const f32x4*>(xrow + c0);
            const f32x4 aa = *reinterpret_cast<const f32x4*>(ca + c0);
            const f32x4 bb = *reinterpret_cast<const f32x4*>(cb + c0);
            s16x4 o;
            for (int j = 0; j < 4; ++j) o[j] = f2b(v[j] * aa[j] + bb[j]);
            *reinterpret_cast<s16x4*>(&At[r][c0]) = o;
        }
    }

    for (int z = 0; z < 3; ++z) {
        f32x4 acc[4][4];
        for (int mi = 0; mi < 4; ++mi)
            for (int ni = 0; ni < 4; ++ni) acc[mi][ni] = (f32x4){0.f, 0.f, 0.f, 0.f};
        const short* wz = wt + z * 65536;
        for (int kt = 0; kt < 8; ++kt) {
            __syncthreads();   // prev reads done (covers At readiness on first pass)
            {
                const short* src = wz + t * 256 + kt * 32;
                for (int ii = 0; ii < 4; ++ii)
                    *reinterpret_cast<s16x8*>(&Bt[t][ii * 8]) =
                        *reinterpret_cast<const s16x8*>(src + ii * 8);
            }
            __syncthreads();
            bfrag af[4];
#pragma unroll
            for (int mi = 0; mi < 4; ++mi)
                af[mi] = *reinterpret_cast<const bfrag*>(&At[mi * 16 + lr][kt * 32 + lh * 8]);
#pragma unroll
            for (int ni = 0; ni < 4; ++ni) {
                const bfrag bf = *reinterpret_cast<const bfrag*>(&Bt[w * 64 + ni * 16 + lr][lh * 8]);
#pragma unroll
                for (int mi = 0; mi < 4; ++mi)
                    acc[mi][ni] = __builtin_amdgcn_mfma_f32_16x16x32_bf16(af[mi], bf, acc[mi][ni], 0, 0, 0);
            }
        }
        // epilogue
        short* outp = (z == 0) ? qo : (z == 1) ? ko : vo;
        const float* bias = (z == 0) ? bq : (z == 1) ? bk : bv;
        const float s = (z == 0) ? QSC : 1.0f;
        for (int ni = 0; ni < 4; ++ni) {
            const int col = w * 64 + ni * 16 + lr;
            const float bsc = bias[col] * s;
            for (int mi = 0; mi < 4; ++mi) {
                const int row = m0 + mi * 16 + lh * 4;
                for (int j = 0; j < 4; ++j)
                    outp[(row + j) * 256 + col] = f2b(acc[mi][ni][j] * s + bsc);
            }
        }
    }
}

// ---------------------------------------------------------------------------
// K3: flash attention.  grid = 32 b * 16 q-tiles, 256 thr = 4 waves.
// Each wave owns 16 q-rows; K/V tiles of 64 keys staged in LDS.
// q already carries the 1/16 scale.
// ---------------------------------------------------------------------------
__global__ __launch_bounds__(256) void attn(const short* __restrict__ qq,
                                            const short* __restrict__ kk,
                                            const short* __restrict__ vv,
                                            short* __restrict__ ao) {
    __shared__ short Kt[64][264];    // [key][c]
    __shared__ short Vt[256][72];    // [c][key]  (transposed)
    __shared__ short Pl[4][16][72];  // per-wave P staging

    const int t = threadIdx.x;
    const int b = blockIdx.x >> 4, qt = blockIdx.x & 15;
    const int w = t >> 6, lane = t & 63;
    const int lr = lane & 15, lh = lane >> 4;
    const int qr0 = qt * 64 + w * 16;

    // Q fragments in registers
    bfrag qf[8];
    {
        const short* qp = qq + (((b << 10) + qr0 + lr) << 8) + lh * 8;
#pragma unroll
        for (int ks = 0; ks < 8; ++ks)
            qf[ks] = *reinterpret_cast<const bfrag*>(qp + ks * 32);
    }

    f32x4 o[16];
    for (int ci = 0; ci < 16; ++ci) o[ci] = (f32x4){0.f, 0.f, 0.f, 0.f};
    float m[4]    = {-3e38f, -3e38f, -3e38f, -3e38f};
    float lsum[4] = {0.f, 0.f, 0.f, 0.f};

    for (int kt = 0; kt < 16; ++kt) {
        // load K tile [64][256]
        {
            const int r = t >> 2, q4 = t & 3;
            const short* kp = kk + (((b << 10) + kt * 64 + r) << 8);
            for (int i = 0; i < 8; ++i) {
                const int c0 = (q4 + 4 * i) * 8;
                *reinterpret_cast<s16x8*>(&Kt[r][c0]) = *reinterpret_cast<const s16x8*>(kp + c0);
            }
        }
        // load V tile transposed -> Vt[c][key]
        {
            const int n = t & 63, c8 = t >> 6;
            const short* vp = vv + (((b << 10) + kt * 64 + n) << 8);
            for (int i = 0; i < 8; ++i) {
                const int c0 = (c8 + 4 * i) * 8;
                const s16x8 vx = *reinterpret_cast<const s16x8*>(vp + c0);
                for (int j = 0; j < 8; ++j) Vt[c0 + j][n] = vx[j];
            }
        }
        __syncthreads();

        // S = q . k^T  (16 q-rows x 64 keys per wave)
        f32x4 sacc[4];
#pragma unroll
        for (int ni = 0; ni < 4; ++ni) sacc[ni] = (f32x4){0.f, 0.f, 0.f, 0.f};
#pragma unroll
        for (int ks = 0; ks < 8; ++ks) {
#pragma unroll
            for (int ni = 0; ni < 4; ++ni) {
                const bfrag bf = *reinterpret_cast<const bfrag*>(&Kt[ni * 16 + lr][ks * 32 + lh * 8]);
                sacc[ni] = __builtin_amdgcn_mfma_f32_16x16x32_bf16(qf[ks], bf, sacc[ni], 0, 0, 0);
            }
        }

        // online softmax (rows = lh*4 + j)
        float p[4][4];
#pragma unroll
        for (int j = 0; j < 4; ++j) {
            float rm = fmaxf(fmaxf(sacc[0][j], sacc[1][j]), fmaxf(sacc[2][j], sacc[3][j]));
            rm = fmaxf(rm, __shfl_xor(rm, 1));
            rm = fmaxf(rm, __shfl_xor(rm, 2));
            rm = fmaxf(rm, __shfl_xor(rm, 4));
            rm = fmaxf(rm, __shfl_xor(rm, 8));
            const float mn = fmaxf(m[j], rm);
            const float sc = __expf(m[j] - mn);
            m[j] = mn;
            float rs = 0.f;
#pragma unroll
            for (int ni = 0; ni < 4; ++ni) { p[ni][j] = __expf(sacc[ni][j] - mn); rs += p[ni][j]; }
            rs += __shfl_xor(rs, 1); rs += __shfl_xor(rs, 2);
            rs += __shfl_xor(rs, 4); rs += __shfl_xor(rs, 8);
            lsum[j] = lsum[j] * sc + rs;
#pragma unroll
            for (int ci = 0; ci < 16; ++ci) o[ci][j] *= sc;
        }

        // stage P (bf16) for MFMA A-operand reads
#pragma unroll
        for (int ni = 0; ni < 4; ++ni)
#pragma unroll
            for (int j = 0; j < 4; ++j)
                Pl[w][lh * 4 + j][ni * 16 + lr] = f2b(p[ni][j]);
        __syncthreads();

        // O += P . V
        const bfrag pa0 = *reinterpret_cast<const bfrag*>(&Pl[w][lr][lh * 8]);
        const bfrag pa1 = *reinterpret_cast<const bfrag*>(&Pl[w][lr][32 + lh * 8]);
#pragma unroll
        for (int ci = 0; ci < 16; ++ci) {
            const bfrag vb0 = *reinterpret_cast<const bfrag*>(&Vt[ci * 16 + lr][lh * 8]);
            const bfrag vb1 = *reinterpret_cast<const bfrag*>(&Vt[ci * 16 + lr][32 + lh * 8]);
            o[ci] = __builtin_amdgcn_mfma_f32_16x16x32_bf16(pa0, vb0, o[ci], 0, 0, 0);
            o[ci] = __builtin_amdgcn_mfma_f32_16x16x32_bf16(pa1, vb1, o[ci], 0, 0, 0);
        }
        __syncthreads();
    }

    // normalize + store
    for (int j = 0; j < 4; ++j) {
        const float inv = 1.0f / lsum[j];
        const int row = (b << 10) + qr0 + lh * 4 + j;
        for (int ci = 0; ci < 16; ++ci)
            ao[(row << 8) + ci * 16 + lr] = f2b(o[ci][j] * inv);
    }
}

// ---------------------------------------------------------------------------
// K4: output projection + bias + residual.  Same tiling as K2, single output.
// ---------------------------------------------------------------------------
__global__ __launch_bounds__(256) void oproj(const short* __restrict__ ao,
                                             const short* __restrict__ wto,   // [256 n][256 k]
                                             const float* __restrict__ bo,
                                             const float* __restrict__ x,
                                             float* __restrict__ out) {
    __shared__ short At[64][264];
    __shared__ short Bt[256][40];

    const int t  = threadIdx.x;
    const int m0 = blockIdx.x * 64;
    const int lane = t & 63, w = t >> 6;
    const int lr = lane & 15, lh = lane >> 4;

    {
        const int r = t >> 2, q4 = t & 3;
        const short* ap = ao + (m0 + r) * 256;
        for (int i = 0; i < 8; ++i) {
            const int c0 = (q4 + 4 * i) * 8;
            *reinterpret_cast<s16x8*>(&At[r][c0]) = *reinterpret_cast<const s16x8*>(ap + c0);
        }
    }

    f32x4 acc[4][4];
    for (int mi = 0; mi < 4; ++mi)
        for (int ni = 0; ni < 4; ++ni) acc[mi][ni] = (f32x4){0.f, 0.f, 0.f, 0.f};

    for (int kt = 0; kt < 8; ++kt) {
        __syncthreads();
        {
            const short* src = wto + t * 256 + kt * 32;
            for (int ii = 0; ii < 4; ++ii)
                *reinterpret_cast<s16x8*>(&Bt[t][ii * 8]) =
                    *reinterpret_cast<const s16x8*>(src + ii * 8);
        }
        __syncthreads();
        bfrag af[4];
#pragma unroll
        for (int mi = 0; mi < 4; ++mi)
            af[mi] = *reinterpret_cast<const bfrag*>(&At[mi * 16 + lr][kt * 32 + lh * 8]);
#pragma unroll
        for (int ni = 0; ni < 4; ++ni) {
            const bfrag bf = *reinterpret_cast<const bfrag*>(&Bt[w * 64 + ni * 16 + lr][lh * 8]);
#pragma unroll
            for (int mi = 0; mi < 4; ++mi)
                acc[mi][ni] = __builtin_amdgcn_mfma_f32_16x16x32_bf16(af[mi], bf, acc[mi][ni], 0, 0, 0);
        }
    }

    for (int ni = 0; ni < 4; ++ni) {
        const int col = w * 64 + ni * 16 + lr;
        const float bb = bo[col];
        for (int mi = 0; mi < 4; ++mi) {
            const int row = m0 + mi * 16 + lh * 4;
            for (int j = 0; j < 4; ++j) {
                const int idx = (row + j) * 256 + col;
                out[idx] = acc[mi][ni][j] + bb + x[idx];
            }
        }
    }
}

// ---------------------------------------------------------------------------
extern "C" void kernel_launch(void* const* d_in, const int* in_sizes, int n_in,
                              void* d_out, int out_size, void* d_ws, size_t ws_size,
                              hipStream_t stream) {
    const float* x   = (const float*)d_in[0];
    const float* gns = (const float*)d_in[1];
    const float* gnb = (const float*)d_in[2];
    const float* Wq  = (const float*)d_in[3];
    const float* bq  = (const float*)d_in[4];
    const float* Wk  = (const float*)d_in[5];
    const float* bk  = (const float*)d_in[6];
    const float* Wv  = (const float*)d_in[7];
    const float* bv  = (const float*)d_in[8];
    const float* Wo  = (const float*)d_in[9];
    const float* bo  = (const float*)d_in[10];
    float* out = (float*)d_out;

    char* ws = (char*)d_ws;
    short* wt   = (short*)(ws);                        // 4 * 128KB transposed bf16 weights
    float* part = (float*)(ws + 524288);               // 64KB GN partials
    float* cA   = (float*)(ws + 589824);               // 32KB
    float* cB   = (float*)(ws + 622592);               // 32KB
    const size_t MB16 = 16777216;
    short* qb  = (short*)(ws + (1 << 20));
    short* kb  = (short*)(ws + (1 << 20) + MB16);
    short* vb  = (short*)(ws + (1 << 20) + 2 * MB16);
    short* aob = (short*)(ws + (1 << 20) + 3 * MB16);

    hipLaunchKernelGGL(prep_w,   dim3(1024), dim3(256), 0, stream, Wq, Wk, Wv, Wo, wt);
    hipLaunchKernelGGL(gn_part,  dim3(256),  dim3(256), 0, stream, x, part);
    hipLaunchKernelGGL(gn_final, dim3(32),   dim3(256), 0, stream, part, gns, gnb, cA, cB);
    hipLaunchKernelGGL(qkv_gemm, dim3(512),  dim3(256), 0, stream, x, cA, cB, wt, bq, bk, bv, qb, kb, vb);
    hipLaunchKernelGGL(attn,     dim3(512),  dim3(256), 0, stream, qb, kb, vb, aob);
    hipLaunchKernelGGL(oproj,    dim3(512),  dim3(256), 0, stream, aob, wt + 3 * 65536, bo, x, out);
}